// Round 6
// baseline (1146.014 us; speedup 1.0000x reference)
//
#include <hip/hip_runtime.h>
#include <hip/hip_bf16.h>

#define DEV __device__ __forceinline__

typedef __attribute__((ext_vector_type(8))) short short8;
typedef __attribute__((ext_vector_type(4))) float floatx4;

DEV short f2bf(float f) {
  unsigned u = __float_as_uint(f);
  u += 0x7fffu + ((u >> 16) & 1u);
  return (short)(u >> 16);
}
DEV float bf2f(short s) {
  return __uint_as_float(((unsigned)(unsigned short)s) << 16);
}
DEV floatx4 mfma16(short8 a, short8 b, floatx4 c) {
  return __builtin_amdgcn_mfma_f32_16x16x32_bf16(a, b, c, 0, 0, 0);
}
// async global->LDS, 16B per lane, dest = wave-uniform base + lane*16
DEV void gload16(void* lds, const void* g) {
  __builtin_amdgcn_global_load_lds(
      (const __attribute__((address_space(1))) unsigned int*)g,
      (__attribute__((address_space(3))) unsigned int*)lds, 16, 0, 0);
}

// ---------------------------------------------------------------------------
// Weight transpose+convert+scale: src fp32 [K,N] -> dst bf16 [N][kp]
// ---------------------------------------------------------------------------
struct MatDesc { const float* src; int K; int N; int kp; int off; float scale; };
struct MatTable { MatDesc m[36]; };

__global__ __launch_bounds__(256) void wtrans_kernel(MatTable T, short* __restrict__ dst) {
  int mi = blockIdx.y;
  MatDesc d = T.m[mi];
  int tilesx = d.N >> 5, tilesy = d.kp >> 5;
  int tb = blockIdx.x;
  if (tb >= tilesx * tilesy) return;
  int ty = tb / tilesx, tx = tb % tilesx;
  __shared__ float tile[32][33];
  int tid = threadIdx.x;
#pragma unroll
  for (int i = 0; i < 4; ++i) {
    int e = tid + i * 256, lr = e >> 5, lc = e & 31;
    int kk = ty * 32 + lr;
    tile[lr][lc] = (kk < d.K) ? d.src[(size_t)kk * d.N + tx * 32 + lc] : 0.f;
  }
  __syncthreads();
#pragma unroll
  for (int i = 0; i < 4; ++i) {
    int e = tid + i * 256, lr = e >> 5, lc = e & 31;
    dst[(size_t)d.off + (size_t)(tx * 32 + lr) * d.kp + ty * 32 + lc] =
        f2bf(tile[lc][lr] * d.scale);
  }
}

// ---------------------------------------------------------------------------
// NeRF encode -> enc bf16 [32768, 64] (k 48..63 = 0)
// ---------------------------------------------------------------------------
__global__ __launch_bounds__(256) void enc_kernel(const float* __restrict__ pos,
                                                  short* __restrict__ enc) {
  int idx = blockIdx.x * 256 + threadIdx.x;
  int row = idx >> 3, oct = idx & 7;
  float p0 = pos[row * 2], p1 = pos[row * 2 + 1];
  short8 o;
#pragma unroll
  for (int j = 0; j < 8; ++j) {
    int k = oct * 8 + j;
    float val = 0.f;
    if (k < 48) {
      int dd = k / 24, rem = k % 24;
      int trig = rem / 12, f = rem % 12;
      float ang = (dd ? p1 : p0) * exp2f((4.0f / 11.0f) * (float)f);
      val = trig ? __cosf(ang) : __sinf(ang);
    }
    o[j] = f2bf(val);
  }
  *(short8*)&enc[(size_t)row * 64 + oct * 8] = o;
}

// ---------------------------------------------------------------------------
// Fused pos-embed GEMM (enc @ W_pos^T, K=64) + relu + x@W_in + LN(k), LN(v)
// 512 threads = 8 waves; block = 128 rows. LDS 80KB exactly -> 2 blocks/CU.
// Output staged in two 64-row halves (stride 528 = conflict-free writes).
// ---------------------------------------------------------------------------
#define LDA_S 528
__global__ __launch_bounds__(512) void embed2_kernel(
    const short* __restrict__ enc, const short* __restrict__ Wt,  // [512][64]
    const float* __restrict__ b_pos, const float* __restrict__ W_in,
    const float* __restrict__ b_in, const float* __restrict__ x,
    const float* __restrict__ lnk_g, const float* __restrict__ lnk_b,
    const float* __restrict__ lnv_g, const float* __restrict__ lnv_b,
    short* __restrict__ kn, short* __restrict__ vn) {
  __shared__ short SS[40960];  // 80 KB: union {Wl 64K + El 16K} / out-stage 67.6K
  short* Wl = SS;              // 512*64
  short* El = SS + 32768;      // 128*64
  int tid = threadIdx.x;
  int lane = tid & 63, wv = tid >> 6;
  int c = lane & 15, g = lane >> 4;
  int blk = blockIdx.x * 128;
#pragma unroll
  for (int gi = 0; gi < 8; ++gi) {
    int grp = wv * 8 + gi;
    int row = grp * 8 + (lane >> 3), kc = lane & 7;
    gload16(&Wl[grp * 512], &Wt[(size_t)row * 64 + ((kc ^ (row & 7)) * 8)]);
  }
#pragma unroll
  for (int gi = 0; gi < 2; ++gi) {
    int grp = wv * 2 + gi;
    int row = grp * 8 + (lane >> 3), kc = lane & 7;
    gload16(&El[grp * 512], &enc[(size_t)(blk + row) * 64 + ((kc ^ (row & 7)) * 8)]);
  }
  __syncthreads();

  floatx4 acc[32];
  floatx4 zf = {0.f, 0.f, 0.f, 0.f};
#pragma unroll
  for (int nf = 0; nf < 32; ++nf) acc[nf] = zf;
  short8 af[2];
#pragma unroll
  for (int ks = 0; ks < 2; ++ks)
    af[ks] = *(const short8*)&El[(wv * 16 + c) * 64 + ((ks * 4 + g) ^ (c & 7)) * 8];
#pragma unroll
  for (int nf = 0; nf < 32; ++nf) {
#pragma unroll
    for (int ks = 0; ks < 2; ++ks) {
      short8 bf8 = *(const short8*)&Wl[(nf * 16 + c) * 64 + ((ks * 4 + g) ^ (c & 7)) * 8];
      acc[nf] = mfma16(af[ks], bf8, acc[nf]);
    }
  }

  int rowbase = blk + wv * 16 + g * 4;
  float x0[4], x1[4], x2[4];
  float s1[4], q1[4], s2[4], q2[4];
#pragma unroll
  for (int r = 0; r < 4; ++r) {
    x0[r] = x[(size_t)(rowbase + r) * 3];
    x1[r] = x[(size_t)(rowbase + r) * 3 + 1];
    x2[r] = x[(size_t)(rowbase + r) * 3 + 2];
    s1[r] = 0; q1[r] = 0; s2[r] = 0; q2[r] = 0;
  }
#pragma unroll
  for (int nf = 0; nf < 32; ++nf) {
    int col = nf * 16 + c;
    float bp = b_pos[col];
    float w0 = W_in[col], w1 = W_in[512 + col], w2 = W_in[1024 + col], bi = b_in[col];
#pragma unroll
    for (int r = 0; r < 4; ++r) {
      float kk = fmaxf(acc[nf][r] + bp, 0.f);
      float vv = kk + x0[r] * w0 + x1[r] * w1 + x2[r] * w2 + bi;
      acc[nf][r] = kk;
      s1[r] += kk; q1[r] += kk * kk; s2[r] += vv; q2[r] += vv * vv;
    }
  }
  float m1[4], r1[4], m2[4], r2[4];
#pragma unroll
  for (int r = 0; r < 4; ++r) {
#pragma unroll
    for (int msk = 1; msk < 16; msk <<= 1) {
      s1[r] += __shfl_xor(s1[r], msk); q1[r] += __shfl_xor(q1[r], msk);
      s2[r] += __shfl_xor(s2[r], msk); q2[r] += __shfl_xor(q2[r], msk);
    }
    m1[r] = s1[r] * (1.f / 512.f);
    r1[r] = rsqrtf(q1[r] * (1.f / 512.f) - m1[r] * m1[r] + 1e-5f);
    m2[r] = s2[r] * (1.f / 512.f);
    r2[r] = rsqrtf(q2[r] * (1.f / 512.f) - m2[r] * m2[r] + 1e-5f);
  }

  int halfsel = wv >> 2;                       // 0: rows 0..63, 1: rows 64..127
  int lrow = (wv & 3) * 16 + g * 4;            // local row within half
  // ---- LN(k): two 64-row halves ----
#pragma unroll
  for (int half = 0; half < 2; ++half) {
    __syncthreads();
    if (halfsel == half) {
#pragma unroll
      for (int nf = 0; nf < 32; ++nf) {
        int col = nf * 16 + c;
        float gk = lnk_g[col], bk = lnk_b[col];
#pragma unroll
        for (int r = 0; r < 4; ++r)
          SS[(lrow + r) * LDA_S + col] = f2bf((acc[nf][r] - m1[r]) * r1[r] * gk + bk);
      }
    }
    __syncthreads();
    int gbase = blk + half * 64;
#pragma unroll
    for (int it = 0; it < 8; ++it) {
      int e = it * 512 + tid;
      int row = e >> 6, colc = (e & 63) * 8;
      *(short8*)&kn[(size_t)(gbase + row) * 512 + colc] = *(const short8*)&SS[row * LDA_S + colc];
    }
  }
  // ---- LN(v): two 64-row halves ----
#pragma unroll
  for (int half = 0; half < 2; ++half) {
    __syncthreads();
    if (halfsel == half) {
#pragma unroll
      for (int nf = 0; nf < 32; ++nf) {
        int col = nf * 16 + c;
        float w0 = W_in[col], w1 = W_in[512 + col], w2 = W_in[1024 + col], bi = b_in[col];
        float gv = lnv_g[col], bv = lnv_b[col];
#pragma unroll
        for (int r = 0; r < 4; ++r) {
          float vv = acc[nf][r] + x0[r] * w0 + x1[r] * w1 + x2[r] * w2 + bi;
          SS[(lrow + r) * LDA_S + col] = f2bf((vv - m2[r]) * r2[r] * gv + bv);
        }
      }
    }
    __syncthreads();
    int gbase = blk + half * 64;
#pragma unroll
    for (int it = 0; it < 8; ++it) {
      int e = it * 512 + tid;
      int row = e >> 6, colc = (e & 63) * 8;
      *(short8*)&vn[(size_t)(gbase + row) * 512 + colc] = *(const short8*)&SS[row * LDA_S + colc];
    }
  }
}

// broadcast latents [256,512] -> lat [2048,512] fp32
__global__ void bcast_kernel(const float* __restrict__ latents, float* __restrict__ lat) {
  int i = blockIdx.x * 256 + threadIdx.x;
  lat[i] = latents[i & 131071];
}

// ---------------------------------------------------------------------------
// Shared GEMM epilogue op
// EPI: 0 = bf16 out, 1 = gelu->bf16, 2 = fp32 residual +=, 3 = fp32 out
// ---------------------------------------------------------------------------
template <int EPI>
DEV void epi_store(void* outp, size_t idx, float xv) {
  if (EPI == 0) {
    ((short*)outp)[idx] = f2bf(xv);
  } else if (EPI == 1) {
    float t = 0.7978845608f * (xv + 0.044715f * xv * xv * xv);
    ((short*)outp)[idx] = f2bf(0.5f * xv * (1.f + tanhf(t)));
  } else if (EPI == 2) {
    ((float*)outp)[idx] += xv;
  } else {
    ((float*)outp)[idx] = xv;
  }
}

// ---------------------------------------------------------------------------
// GEMM 128x128 tile, BK=64, 4 waves (2x2). A bf16 [M,*lda]; Wt bf16 [N][K].
// ---------------------------------------------------------------------------
template <int EPI>
__global__ __launch_bounds__(256) void gemm_kernel(
    const short* __restrict__ A, const short* __restrict__ Wt,
    const float* __restrict__ bias, void* __restrict__ outp,
    int M, int N, int K, int lda, int ldo) {
  __shared__ short Alds[128 * 64];
  __shared__ short Blds[128 * 64];
  int tid = threadIdx.x;
  int brow = blockIdx.y * 128, bcol = blockIdx.x * 128;
  int lane = tid & 63, wvid = tid >> 6;
  int wr = wvid >> 1, wc = wvid & 1;
  int g = lane >> 4, c = lane & 15;
  floatx4 zf = {0.f, 0.f, 0.f, 0.f};
  floatx4 acc[4][4];
#pragma unroll
  for (int i = 0; i < 4; ++i)
#pragma unroll
    for (int j = 0; j < 4; ++j) acc[i][j] = zf;

  int srow = (lane >> 3), skc = lane & 7;
  for (int k0 = 0; k0 < K; k0 += 64) {
#pragma unroll
    for (int gi = 0; gi < 4; ++gi) {
      int grp = wvid * 4 + gi;
      int row = grp * 8 + srow;
      int sw = ((skc ^ (row & 7)) * 8);
      gload16(&Alds[grp * 512], &A[(size_t)(brow + row) * lda + k0 + sw]);
      gload16(&Blds[grp * 512], &Wt[(size_t)(bcol + row) * K + k0 + sw]);
    }
    __syncthreads();
#pragma unroll
    for (int ks = 0; ks < 2; ++ks) {
      int slot = ((ks * 4 + g) ^ (c & 7)) * 8;
      short8 af[4], bf8[4];
#pragma unroll
      for (int mf = 0; mf < 4; ++mf)
        af[mf] = *(const short8*)&Alds[(wr * 64 + mf * 16 + c) * 64 + slot];
#pragma unroll
      for (int nf = 0; nf < 4; ++nf)
        bf8[nf] = *(const short8*)&Blds[(wc * 64 + nf * 16 + c) * 64 + slot];
#pragma unroll
      for (int mf = 0; mf < 4; ++mf)
#pragma unroll
        for (int nf = 0; nf < 4; ++nf)
          acc[mf][nf] = mfma16(af[mf], bf8[nf], acc[mf][nf]);
    }
    __syncthreads();
  }

#pragma unroll
  for (int mf = 0; mf < 4; ++mf) {
#pragma unroll
    for (int nf = 0; nf < 4; ++nf) {
      int col = bcol + wc * 64 + nf * 16 + c;
      float bv = bias ? bias[col] : 0.f;
      int row0 = brow + wr * 64 + mf * 16 + g * 4;
#pragma unroll
      for (int r = 0; r < 4; ++r)
        epi_store<EPI>(outp, (size_t)(row0 + r) * ldo + col, acc[mf][nf][r] + bv);
    }
  }
}

// ---------------------------------------------------------------------------
// GEMM 64x64 tile. 4 waves (2x2), each wave 32x32. A bf16.
// ---------------------------------------------------------------------------
template <int EPI>
__global__ __launch_bounds__(256) void gemm64_kernel(
    const short* __restrict__ A, const short* __restrict__ Wt,
    const float* __restrict__ bias, void* __restrict__ outp,
    int M, int N, int K, int lda, int ldo) {
  __shared__ short Alds[64 * 64];
  __shared__ short Blds[64 * 64];
  int tid = threadIdx.x;
  int brow = blockIdx.y * 64, bcol = blockIdx.x * 64;
  int lane = tid & 63, wvid = tid >> 6;
  int wr = wvid >> 1, wc = wvid & 1;
  int g = lane >> 4, c = lane & 15;
  floatx4 zf = {0.f, 0.f, 0.f, 0.f};
  floatx4 acc[2][2];
#pragma unroll
  for (int i = 0; i < 2; ++i)
#pragma unroll
    for (int j = 0; j < 2; ++j) acc[i][j] = zf;

  int srow = (lane >> 3), skc = lane & 7;
  for (int k0 = 0; k0 < K; k0 += 64) {
#pragma unroll
    for (int gi = 0; gi < 2; ++gi) {
      int grp = wvid * 2 + gi;
      int row = grp * 8 + srow;
      int sw = ((skc ^ (row & 7)) * 8);
      gload16(&Alds[grp * 512], &A[(size_t)(brow + row) * lda + k0 + sw]);
      gload16(&Blds[grp * 512], &Wt[(size_t)(bcol + row) * K + k0 + sw]);
    }
    __syncthreads();
#pragma unroll
    for (int ks = 0; ks < 2; ++ks) {
      int slot = ((ks * 4 + g) ^ (c & 7)) * 8;
      short8 af[2], bf8[2];
#pragma unroll
      for (int mf = 0; mf < 2; ++mf)
        af[mf] = *(const short8*)&Alds[(wr * 32 + mf * 16 + c) * 64 + slot];
#pragma unroll
      for (int nf = 0; nf < 2; ++nf)
        bf8[nf] = *(const short8*)&Blds[(wc * 32 + nf * 16 + c) * 64 + slot];
#pragma unroll
      for (int mf = 0; mf < 2; ++mf)
#pragma unroll
        for (int nf = 0; nf < 2; ++nf)
          acc[mf][nf] = mfma16(af[mf], bf8[nf], acc[mf][nf]);
    }
    __syncthreads();
  }

#pragma unroll
  for (int mf = 0; mf < 2; ++mf) {
#pragma unroll
    for (int nf = 0; nf < 2; ++nf) {
      int col = bcol + wc * 32 + nf * 16 + c;
      float bv = bias ? bias[col] : 0.f;
      int row0 = brow + wr * 32 + mf * 16 + g * 4;
#pragma unroll
      for (int r = 0; r < 4; ++r)
        epi_store<EPI>(outp, (size_t)(row0 + r) * ldo + col, acc[mf][nf][r] + bv);
    }
  }
}

// ---------------------------------------------------------------------------
// GEMM 64x64 tile with FUSED LayerNorm on A. A fp32 [M,512]; per-block row
// stats (redundant across col-tiles, L2-hot), reg-staged LN->bf16->ds_write.
// K = 512 fixed. Wt bf16 [N][512].
// ---------------------------------------------------------------------------
template <int EPI>
__global__ __launch_bounds__(256) void gemm64ln_kernel(
    const float* __restrict__ A, const short* __restrict__ Wt,
    const float* __restrict__ lg, const float* __restrict__ lb,
    const float* __restrict__ bias, void* __restrict__ outp,
    int M, int N, int ldo) {
  __shared__ short Alds[64 * 64];
  __shared__ short Blds[64 * 64];
  __shared__ float stats[128];
  int tid = threadIdx.x;
  int brow = blockIdx.y * 64, bcol = blockIdx.x * 64;
  int lane = tid & 63, wvid = tid >> 6;
  int wr = wvid >> 1, wc = wvid & 1;
  int g = lane >> 4, c = lane & 15;

  // LN stats: thread t -> row t>>2, col range (t&3)*128..+128
  {
    int row = tid >> 2, seg = tid & 3;
    const float* ap = &A[(size_t)(brow + row) * 512 + seg * 128];
    float s = 0.f, q = 0.f;
#pragma unroll
    for (int i = 0; i < 32; ++i) {
      floatx4 v = *(const floatx4*)&ap[i * 4];
      s += v[0] + v[1] + v[2] + v[3];
      q += v[0] * v[0] + v[1] * v[1] + v[2] * v[2] + v[3] * v[3];
    }
    s += __shfl_xor(s, 1); s += __shfl_xor(s, 2);
    q += __shfl_xor(q, 1); q += __shfl_xor(q, 2);
    if (seg == 0) {
      float m = s * (1.f / 512.f);
      stats[row] = m;
      stats[64 + row] = rsqrtf(q * (1.f / 512.f) - m * m + 1e-5f);
    }
  }
  __syncthreads();

  floatx4 zf = {0.f, 0.f, 0.f, 0.f};
  floatx4 acc[2][2];
#pragma unroll
  for (int i = 0; i < 2; ++i)
#pragma unroll
    for (int j = 0; j < 2; ++j) acc[i][j] = zf;

  int srow = lane >> 3, skc = lane & 7;
  int arow = tid >> 2, akc2 = (tid & 3) * 2;
  float am = stats[arow], ars = stats[64 + arow];

  for (int k0 = 0; k0 < 512; k0 += 64) {
    // stage A with LN applied (reg path, swizzled ds_write)
#pragma unroll
    for (int kk = 0; kk < 2; ++kk) {
      int kc = akc2 + kk;
      int cb = k0 + kc * 8;
      floatx4 v0 = *(const floatx4*)&A[(size_t)(brow + arow) * 512 + cb];
      floatx4 v1 = *(const floatx4*)&A[(size_t)(brow + arow) * 512 + cb + 4];
      floatx4 g0 = *(const floatx4*)&lg[cb];
      floatx4 g1 = *(const floatx4*)&lg[cb + 4];
      floatx4 b0 = *(const floatx4*)&lb[cb];
      floatx4 b1 = *(const floatx4*)&lb[cb + 4];
      short8 o;
#pragma unroll
      for (int j = 0; j < 4; ++j) {
        o[j]     = f2bf((v0[j] - am) * ars * g0[j] + b0[j]);
        o[4 + j] = f2bf((v1[j] - am) * ars * g1[j] + b1[j]);
      }
      int slot = kc ^ (arow & 7);
      *(short8*)&Alds[arow * 64 + slot * 8] = o;
    }
    // stage B via gload16
#pragma unroll
    for (int gi = 0; gi < 2; ++gi) {
      int grp = wvid * 2 + gi;
      int row = grp * 8 + srow;
      int sw = ((skc ^ (row & 7)) * 8);
      gload16(&Blds[grp * 512], &Wt[(size_t)(bcol + row) * 512 + k0 + sw]);
    }
    __syncthreads();
#pragma unroll
    for (int ks = 0; ks < 2; ++ks) {
      int slot = ((ks * 4 + g) ^ (c & 7)) * 8;
      short8 af[2], bf8[2];
#pragma unroll
      for (int mf = 0; mf < 2; ++mf)
        af[mf] = *(const short8*)&Alds[(wr * 32 + mf * 16 + c) * 64 + slot];
#pragma unroll
      for (int nf = 0; nf < 2; ++nf)
        bf8[nf] = *(const short8*)&Blds[(wc * 32 + nf * 16 + c) * 64 + slot];
#pragma unroll
      for (int mf = 0; mf < 2; ++mf)
#pragma unroll
        for (int nf = 0; nf < 2; ++nf)
          acc[mf][nf] = mfma16(af[mf], bf8[nf], acc[mf][nf]);
    }
    __syncthreads();
  }

#pragma unroll
  for (int mf = 0; mf < 2; ++mf) {
#pragma unroll
    for (int nf = 0; nf < 2; ++nf) {
      int col = bcol + wc * 32 + nf * 16 + c;
      float bv = bias ? bias[col] : 0.f;
      int row0 = brow + wr * 32 + mf * 16 + g * 4;
#pragma unroll
      for (int r = 0; r < 4; ++r)
        epi_store<EPI>(outp, (size_t)(row0 + r) * ldo + col, acc[mf][nf][r] + bv);
    }
  }
}

// ---------------------------------------------------------------------------
// Split-KV flash attention, 128-row Q tile, 8 waves (wave = 16 q rows).
// Q pre-scaled by DH^-0.5 (folded into Wq). qbrows==0 => q shared across b.
// po[(seg*2048 + b*256 + row)*512 + h*64 + d]; pm/pl[(seg*2048+b*256+row)*8+h]
// ---------------------------------------------------------------------------
__global__ __launch_bounds__(512) void flashsp_kernel(
    const short* __restrict__ q, const short* __restrict__ k,
    const short* __restrict__ v, float* __restrict__ po,
    float* __restrict__ pm, float* __restrict__ pl,
    int qrs, int qbrows, long kvbstride, int kvrstride,
    int seglen, int lognseg) {
  __shared__ short Qs[128 * 64];
  __shared__ short Ks[64 * 64];
  __shared__ short Vt[64 * 72];
  __shared__ short Ps[128 * 72];
  int tid = threadIdx.x;
  int bz = blockIdx.z;
  int b = bz >> lognseg, seg = bz & ((1 << lognseg) - 1);
  int h = blockIdx.y, qt = blockIdx.x;
  int lane = tid & 63, wv = tid >> 6;
  int g = lane >> 4, c = lane & 15;
  int srow = lane >> 3, skc = lane & 7;

#pragma unroll
  for (int gi = 0; gi < 2; ++gi) {
    int grp = wv * 2 + gi;
    int row = grp * 8 + srow;
    int sw = ((skc ^ (row & 7)) * 8);
    gload16(&Qs[grp * 512],
            &q[((size_t)(b * qbrows) + qt * 128 + row) * qrs + h * 64 + sw]);
  }

  float m_[4], l_[4];
  floatx4 zf = {0.f, 0.f, 0.f, 0.f};
  floatx4 o_[4];
#pragma unroll
  for (int r = 0; r < 4; ++r) { m_[r] = -3.0e38f; l_[r] = 0.f; }
#pragma unroll
  for (int f = 0; f < 4; ++f) o_[f] = zf;

  int tbeg = seg * seglen, tend = tbeg + seglen;
  for (int t0 = tbeg; t0 < tend; t0 += 64) {
    {
      int row = wv * 8 + srow;
      int sw = ((skc ^ (row & 7)) * 8);
      gload16(&Ks[wv * 512],
              &k[(size_t)b * kvbstride + (size_t)(t0 + row) * kvrstride + h * 64 + sw]);
    }
    {
      int j = tid >> 3, f0 = (tid & 7) * 8, mm = tid & 7, tg = j >> 3;
      short8 tv = *(const short8*)&v[(size_t)b * kvbstride + (size_t)(t0 + j) * kvrstride + h * 64 + f0];
#pragma unroll
      for (int jj = 0; jj < 8; ++jj)
        Vt[(f0 + jj) * 72 + ((tg ^ mm) * 8) + (j & 7)] = tv[jj];
    }
    __syncthreads();

    floatx4 s[4];
#pragma unroll
    for (int f = 0; f < 4; ++f) s[f] = zf;
#pragma unroll
    for (int ks = 0; ks < 2; ++ks) {
      int slot = ((ks * 4 + g) ^ (c & 7)) * 8;
      short8 a = *(const short8*)&Qs[(wv * 16 + c) * 64 + slot];
#pragma unroll
      for (int f = 0; f < 4; ++f) {
        short8 b8 = *(const short8*)&Ks[(f * 16 + c) * 64 + slot];
        s[f] = mfma16(a, b8, s[f]);
      }
    }

    float nm[4], sf[4], rs[4];
#pragma unroll
    for (int r = 0; r < 4; ++r) {
      float t = fmaxf(fmaxf(s[0][r], s[1][r]), fmaxf(s[2][r], s[3][r]));
#pragma unroll
      for (int msk = 1; msk < 16; msk <<= 1) t = fmaxf(t, __shfl_xor(t, msk));
      nm[r] = fmaxf(m_[r], t);
      sf[r] = __expf(m_[r] - nm[r]);
      rs[r] = 0.f;
    }
#pragma unroll
    for (int f = 0; f < 4; ++f)
#pragma unroll
      for (int r = 0; r < 4; ++r) {
        float p = __expf(s[f][r] - nm[r]);
        s[f][r] = p; rs[r] += p;
      }
#pragma unroll
    for (int r = 0; r < 4; ++r) {
#pragma unroll
      for (int msk = 1; msk < 16; msk <<= 1) rs[r] += __shfl_xor(rs[r], msk);
      l_[r] = l_[r] * sf[r] + rs[r];
      m_[r] = nm[r];
    }
#pragma unroll
    for (int f = 0; f < 4; ++f)
#pragma unroll
      for (int r = 0; r < 4; ++r) o_[f][r] *= sf[r];
#pragma unroll
    for (int f = 0; f < 4; ++f)
#pragma unroll
      for (int r = 0; r < 4; ++r)
        Ps[(wv * 16 + g * 4 + r) * 72 + f * 16 + c] = f2bf(s[f][r]);
    __syncthreads();
#pragma unroll
    for (int ks = 0; ks < 2; ++ks) {
      short8 pa = *(const short8*)&Ps[(wv * 16 + c) * 72 + ks * 32 + g * 8];
#pragma unroll
      for (int f = 0; f < 4; ++f) {
        int mm = (2 * f + (c >> 3)) & 7;
        short8 vb = *(const short8*)&Vt[(f * 16 + c) * 72 + ((ks * 4 + g) ^ mm) * 8];
        o_[f] = mfma16(pa, vb, o_[f]);
      }
    }
    __syncthreads();
  }

#pragma unroll
  for (int f = 0; f < 4; ++f)
#pragma unroll
    for (int r = 0; r < 4; ++r) {
      int row = qt * 128 + wv * 16 + g * 4 + r;
      size_t grow = (size_t)seg * 2048 + b * 256 + row;
      po[grow * 512 + h * 64 + f * 16 + c] = o_[f][r];
      if (f == 0 && c == 0) {
        pm[grow * 8 + h] = m_[r];
        pl[grow * 8 + h] = l_[r];
      }
    }
}

// ---------------------------------------------------------------------------
// Combine NSEG partial attention results -> bf16 out [2048,512]
// ---------------------------------------------------------------------------
template <int NSEG>
__global__ __launch_bounds__(256) void fcomb_kernel(
    const float* __restrict__ po, const float* __restrict__ pm,
    const float* __restrict__ pl, short* __restrict__ out) {
  int idx = blockIdx.x * 256 + threadIdx.x;  // over 2048*512
  int grow = idx >> 9, col = idx & 511, h = col >> 6;
  float ms[NSEG];
  float M = -3.0e38f;
#pragma unroll
  for (int s = 0; s < NSEG; ++s) {
    ms[s] = pm[((size_t)s * 2048 + grow) * 8 + h];
    M = fmaxf(M, ms[s]);
  }
  float L = 0.f, acc = 0.f;
#pragma unroll
  for (int s = 0; s < NSEG; ++s) {
    float w = __expf(ms[s] - M);
    L += w * pl[((size_t)s * 2048 + grow) * 8 + h];
    acc += w * po[((size_t)s * 2048 + grow) * 512 + col];
  }
  out[idx] = f2bf(acc / L);
}

// ---------------------------------------------------------------------------
extern "C" void kernel_launch(void* const* d_in, const int* in_sizes, int n_in,
                              void* d_out, int out_size, void* d_ws, size_t ws_size,
                              hipStream_t stream) {
  const float* x       = (const float*)d_in[0];
  const float* pos     = (const float*)d_in[1];
  const float* W_pos   = (const float*)d_in[2];
  const float* b_pos   = (const float*)d_in[3];
  const float* W_in    = (const float*)d_in[4];
  const float* b_in    = (const float*)d_in[5];
  const float* latents = (const float*)d_in[6];
  const float* lnq_g   = (const float*)d_in[7];
  const float* lnq_b   = (const float*)d_in[8];
  const float* lnk_g   = (const float*)d_in[9];
  const float* lnk_b   = (const float*)d_in[10];
  const float* lnv_g   = (const float*)d_in[11];
  const float* lnv_b   = (const float*)d_in[12];
  const float* cWq     = (const float*)d_in[13];
  const float* cWk     = (const float*)d_in[14];
  const float* cWv     = (const float*)d_in[15];
  const float* cWo     = (const float*)d_in[16];
  const float* c_bo    = (const float*)d_in[17];
  const float* ln1_g   = (const float*)d_in[18];
  const float* ln1_b   = (const float*)d_in[19];
  const float* sWq     = (const float*)d_in[20];
  const float* sWkv    = (const float*)d_in[21];
  const float* sWo     = (const float*)d_in[22];
  const float* s_bo    = (const float*)d_in[23];
  const float* ln2_g   = (const float*)d_in[24];
  const float* ln2_b   = (const float*)d_in[25];
  const float* fW1     = (const float*)d_in[26];
  const float* f_b1    = (const float*)d_in[27];
  const float* fW2     = (const float*)d_in[28];
  const float* f_b2    = (const float*)d_in[29];
  const float* lnf_g   = (const float*)d_in[30];
  const float* lnf_b   = (const float*)d_in[31];
  const float* Wb      = (const float*)d_in[32];
  const float* bbv     = (const float*)d_in[33];
  float* outp = (float*)d_out;

  // bf16 transposed weight offsets (elements)
  size_t W = 0;
  size_t o_cWq = W; W += 512 * 512;
  size_t o_cWk = W; W += 512 * 512;
  size_t o_cWv = W; W += 512 * 512;
  size_t o_cWo = W; W += 512 * 512;
  size_t o_Wb  = W; W += 64 * 512;
  size_t o_Wpos = W; W += 512 * 64;
  size_t o_sQKV[6], o_sWo[6], o_fW1[6], o_fW2[6];
  for (int i = 0; i < 6; ++i) {
    o_sQKV[i] = W; W += 1536 * 512;   // q rows 0..511 (pre-scaled), kv rows 512..1535
    o_sWo[i]  = W; W += 512 * 512;
    o_fW1[i]  = W; W += 2048 * 512;
    o_fW2[i]  = W; W += 512 * 2048;
  }
  MatTable T;
  int nm = 0;
  auto add = [&](const float* s, int K, int N, int kp, size_t off, float sc) {
    T.m[nm].src = s; T.m[nm].K = K; T.m[nm].N = N; T.m[nm].kp = kp;
    T.m[nm].off = (int)off; T.m[nm].scale = sc; ++nm;
  };
  const float SC = 0.125f;  // DH^-0.5 folded into Wq
  add(cWq, 512, 512, 512, o_cWq, SC); add(cWk, 512, 512, 512, o_cWk, 1.f);
  add(cWv, 512, 512, 512, o_cWv, 1.f); add(cWo, 512, 512, 512, o_cWo, 1.f);
  add(Wb, 512, 64, 512, o_Wb, 1.f);
  add(W_pos, 48, 512, 64, o_Wpos, 1.f);
  for (int i = 0; i < 6; ++i) {
    add(sWq  + (size_t)i * 512 * 512,  512, 512,  512, o_sQKV[i], SC);
    add(sWkv + (size_t)i * 512 * 1024, 512, 1024, 512, o_sQKV[i] + 512 * 512, 1.f);
    add(sWo  + (size_t)i * 512 * 512,  512, 512,  512, o_sWo[i], 1.f);
    add(fW1  + (size_t)i * 512 * 2048, 512, 2048, 512, o_fW1[i], 1.f);
    add(fW2  + (size_t)i * 2048 * 512, 2048, 512, 2048, o_fW2[i], 1.f);
  }

  // workspace carve
  char* p = (char*)d_ws;
  auto carve = [&](size_t bytes) {
    char* r = p; p += (bytes + 255) & ~(size_t)255; return r;
  };
  short* wtb   = (short*)carve(W * 2);                     // ~40MB
  short* enc   = (short*)carve((size_t)32768 * 64 * 2);    // 4MB
  short* kn    = (short*)carve(33554432);                  // 32MB
  short* vn    = (short*)carve(33554432);                  // 32MB (contiguous after kn)
  short* kvc   = (short*)carve((size_t)32768 * 1024 * 2);  // 64MB  [K | V]
  short* qc    = (short*)carve(262144);
  float* lat   = (float*)carve(4194304);
  float* pm    = (float*)carve(1048576);
  float* pl    = (float*)carve(1048576);
  // aliases into dead regions:
  short* attno = enc;                                  // enc dead after embed2
  float* po    = (float*)kn;                           // kn/vn dead after projections
  short* qkv   = (short*)((char*)kn + 40 * 1048576);   // 6MB (inside vn)
  short* ffh   = (short*)((char*)kn + 48 * 1048576);   // 8MB (inside vn)

  wtrans_kernel<<<dim3(1024, 36), 256, 0, stream>>>(T, wtb);
  enc_kernel<<<1024, 256, 0, stream>>>(pos, enc);
  embed2_kernel<<<256, 512, 0, stream>>>(enc, wtb + o_Wpos, b_pos, W_in, b_in, x,
                                         lnk_g, lnk_b, lnv_g, lnv_b, kn, vn);
  bcast_kernel<<<4096, 256, 0, stream>>>(latents, lat);
  // qc = LN(latents) @ (cWq * SC)  [fused LN]
  gemm64ln_kernel<0><<<dim3(8, 4), 256, 0, stream>>>(latents, wtb + o_cWq, lnq_g, lnq_b,
                                                     nullptr, qc, 256, 512, 512);
  gemm_kernel<0><<<dim3(4, 256), 256, 0, stream>>>(kn, wtb + o_cWk, nullptr, kvc, 32768, 512, 512, 512, 1024);
  gemm_kernel<0><<<dim3(4, 256), 256, 0, stream>>>(vn, wtb + o_cWv, nullptr, kvc + 512, 32768, 512, 512, 512, 1024);
  // cross attention: 8 KV segments of 512 tokens, 128-row Q tiles; q shared (qbrows=0)
  flashsp_kernel<<<dim3(2, 8, 64), 512, 0, stream>>>(qc, kvc, kvc + 512, po, pm, pl,
                                                     512, 0, (long)4096 * 1024, 1024, 512, 3);
  fcomb_kernel<8><<<4096, 256, 0, stream>>>(po, pm, pl, attno);
  gemm64_kernel<2><<<dim3(8, 32), 256, 0, stream>>>(attno, wtb + o_cWo, c_bo, lat, 2048, 512, 512, 512, 512);

  for (int i = 0; i < 6; ++i) {
    // qkv = LN1(lat) @ sQKV   [fused LN]
    gemm64ln_kernel<0><<<dim3(24, 32), 256, 0, stream>>>(lat, wtb + o_sQKV[i],
                                                         ln1_g + i * 512, ln1_b + i * 512,
                                                         nullptr, qkv, 2048, 1536, 1536);
    // self attention: 4 KV segments of 64 tokens, 128-row Q tiles (per-batch q)
    flashsp_kernel<<<dim3(2, 8, 32), 512, 0, stream>>>(qkv, qkv + 512, qkv + 1024, po, pm, pl,
                                                       1536, 256, (long)256 * 1536, 1536, 64, 2);
    fcomb_kernel<4><<<4096, 256, 0, stream>>>(po, pm, pl, attno);
    gemm64_kernel<2><<<dim3(8, 32), 256, 0, stream>>>(attno, wtb + o_sWo[i], s_bo + i * 512, lat, 2048, 512, 512, 512, 512);
    // ffh = gelu(LN2(lat) @ fW1)   [fused LN]
    gemm64ln_kernel<1><<<dim3(32, 32), 256, 0, stream>>>(lat, wtb + o_fW1[i],
                                                         ln2_g + i * 512, ln2_b + i * 512,
                                                         f_b1 + i * 2048, ffh, 2048, 2048, 2048);
    gemm64_kernel<2><<<dim3(8, 32), 256, 0, stream>>>(ffh, wtb + o_fW2[i], f_b2 + i * 512, lat, 2048, 512, 2048, 2048, 512);
  }
  // out = LN_f(lat) @ Wb + bb   [fused LN]
  gemm64ln_kernel<3><<<dim3(1, 32), 256, 0, stream>>>(lat, wtb + o_Wb, lnf_g, lnf_b,
                                                      bbv, outp, 2048, 64, 64);
}

// Round 7
// 818.445 us; speedup vs baseline: 1.4002x; 1.4002x over previous
//
#include <hip/hip_runtime.h>
#include <hip/hip_bf16.h>

#define DEV __device__ __forceinline__

typedef __attribute__((ext_vector_type(8))) short short8;
typedef __attribute__((ext_vector_type(4))) float floatx4;

DEV short f2bf(float f) {
  unsigned u = __float_as_uint(f);
  u += 0x7fffu + ((u >> 16) & 1u);
  return (short)(u >> 16);
}
DEV float bf2f(short s) {
  return __uint_as_float(((unsigned)(unsigned short)s) << 16);
}
DEV float wred(float v) {
#pragma unroll
  for (int m = 1; m < 64; m <<= 1) v += __shfl_xor(v, m);
  return v;
}
DEV floatx4 mfma16(short8 a, short8 b, floatx4 c) {
  return __builtin_amdgcn_mfma_f32_16x16x32_bf16(a, b, c, 0, 0, 0);
}
// async global->LDS, 16B per lane, dest = wave-uniform base + lane*16
DEV void gload16(void* lds, const void* g) {
  __builtin_amdgcn_global_load_lds(
      (const __attribute__((address_space(1))) unsigned int*)g,
      (__attribute__((address_space(3))) unsigned int*)lds, 16, 0, 0);
}

// ---------------------------------------------------------------------------
// Weight transpose+convert+scale: src fp32 [K,N] -> dst bf16 [N][kp]
// ---------------------------------------------------------------------------
struct MatDesc { const float* src; int K; int N; int kp; int off; float scale; };
struct MatTable { MatDesc m[36]; };

__global__ __launch_bounds__(256) void wtrans_kernel(MatTable T, short* __restrict__ dst) {
  int mi = blockIdx.y;
  MatDesc d = T.m[mi];
  int tilesx = d.N >> 5, tilesy = d.kp >> 5;
  int tb = blockIdx.x;
  if (tb >= tilesx * tilesy) return;
  int ty = tb / tilesx, tx = tb % tilesx;
  __shared__ float tile[32][33];
  int tid = threadIdx.x;
#pragma unroll
  for (int i = 0; i < 4; ++i) {
    int e = tid + i * 256, lr = e >> 5, lc = e & 31;
    int kk = ty * 32 + lr;
    tile[lr][lc] = (kk < d.K) ? d.src[(size_t)kk * d.N + tx * 32 + lc] : 0.f;
  }
  __syncthreads();
#pragma unroll
  for (int i = 0; i < 4; ++i) {
    int e = tid + i * 256, lr = e >> 5, lc = e & 31;
    dst[(size_t)d.off + (size_t)(tx * 32 + lr) * d.kp + ty * 32 + lc] =
        f2bf(tile[lc][lr] * d.scale);
  }
}

// ---------------------------------------------------------------------------
// NeRF encode -> enc bf16 [32768, 64] (k 48..63 = 0)
// ---------------------------------------------------------------------------
__global__ __launch_bounds__(256) void enc_kernel(const float* __restrict__ pos,
                                                  short* __restrict__ enc) {
  int idx = blockIdx.x * 256 + threadIdx.x;
  int row = idx >> 3, oct = idx & 7;
  float p0 = pos[row * 2], p1 = pos[row * 2 + 1];
  short8 o;
#pragma unroll
  for (int j = 0; j < 8; ++j) {
    int k = oct * 8 + j;
    float val = 0.f;
    if (k < 48) {
      int dd = k / 24, rem = k % 24;
      int trig = rem / 12, f = rem % 12;
      float ang = (dd ? p1 : p0) * exp2f((4.0f / 11.0f) * (float)f);
      val = trig ? __cosf(ang) : __sinf(ang);
    }
    o[j] = f2bf(val);
  }
  *(short8*)&enc[(size_t)row * 64 + oct * 8] = o;
}

// ---------------------------------------------------------------------------
// Fused pos-embed GEMM (enc @ W_pos^T, K=64) + relu + x@W_in + LN(k), LN(v)
// 512 threads = 8 waves; block = 128 rows; wave = 16 rows x 512 cols.
// All per-column params staged in LDS (kills the ~416 VMEM loads/thread wall).
// Output: knvn [32768][1024], LN(k) cols 0..511, LN(v) cols 512..1023.
// ---------------------------------------------------------------------------
__global__ __launch_bounds__(512) void embed2_kernel(
    const short* __restrict__ enc, const short* __restrict__ Wt,  // [512][64]
    const float* __restrict__ b_pos, const float* __restrict__ W_in,
    const float* __restrict__ b_in, const float* __restrict__ x,
    const float* __restrict__ lnk_g, const float* __restrict__ lnk_b,
    const float* __restrict__ lnv_g, const float* __restrict__ lnv_b,
    short* __restrict__ knvn) {
  __shared__ short Wl[512 * 64];   // 64 KB
  __shared__ short El[128 * 64];   // 16 KB
  __shared__ float Pf[9 * 512];    // 18 KB params
  int tid = threadIdx.x;
  int lane = tid & 63, wv = tid >> 6;
  int c = lane & 15, g = lane >> 4;
  int blk = blockIdx.x * 128;
#pragma unroll
  for (int gi = 0; gi < 8; ++gi) {
    int grp = wv * 8 + gi;
    int row = grp * 8 + (lane >> 3), kc = lane & 7;
    gload16(&Wl[grp * 512], &Wt[(size_t)row * 64 + ((kc ^ (row & 7)) * 8)]);
  }
#pragma unroll
  for (int gi = 0; gi < 2; ++gi) {
    int grp = wv * 2 + gi;
    int row = grp * 8 + (lane >> 3), kc = lane & 7;
    gload16(&El[grp * 512], &enc[(size_t)(blk + row) * 64 + ((kc ^ (row & 7)) * 8)]);
  }
  Pf[tid]        = b_pos[tid];
  Pf[512 + tid]  = W_in[tid];
  Pf[1024 + tid] = W_in[512 + tid];
  Pf[1536 + tid] = W_in[1024 + tid];
  Pf[2048 + tid] = b_in[tid];
  Pf[2560 + tid] = lnk_g[tid];
  Pf[3072 + tid] = lnk_b[tid];
  Pf[3584 + tid] = lnv_g[tid];
  Pf[4096 + tid] = lnv_b[tid];
  __syncthreads();

  floatx4 acc[32];
  floatx4 zf = {0.f, 0.f, 0.f, 0.f};
#pragma unroll
  for (int nf = 0; nf < 32; ++nf) acc[nf] = zf;
  short8 af[2];
#pragma unroll
  for (int ks = 0; ks < 2; ++ks)
    af[ks] = *(const short8*)&El[(wv * 16 + c) * 64 + ((ks * 4 + g) ^ (c & 7)) * 8];
#pragma unroll
  for (int nf = 0; nf < 32; ++nf) {
#pragma unroll
    for (int ks = 0; ks < 2; ++ks) {
      short8 bf8 = *(const short8*)&Wl[(nf * 16 + c) * 64 + ((ks * 4 + g) ^ (c & 7)) * 8];
      acc[nf] = mfma16(af[ks], bf8, acc[nf]);
    }
  }

  int rowbase = blk + wv * 16 + g * 4;
  float x0[4], x1[4], x2[4];
  float s1[4], q1[4], s2[4], q2[4];
#pragma unroll
  for (int r = 0; r < 4; ++r) {
    x0[r] = x[(size_t)(rowbase + r) * 3];
    x1[r] = x[(size_t)(rowbase + r) * 3 + 1];
    x2[r] = x[(size_t)(rowbase + r) * 3 + 2];
    s1[r] = 0; q1[r] = 0; s2[r] = 0; q2[r] = 0;
  }
#pragma unroll
  for (int nf = 0; nf < 32; ++nf) {
    int col = nf * 16 + c;
    float bp = Pf[col];
    float w0 = Pf[512 + col], w1 = Pf[1024 + col], w2 = Pf[1536 + col], bi = Pf[2048 + col];
#pragma unroll
    for (int r = 0; r < 4; ++r) {
      float kk = fmaxf(acc[nf][r] + bp, 0.f);
      float vv = kk + x0[r] * w0 + x1[r] * w1 + x2[r] * w2 + bi;
      acc[nf][r] = kk;
      s1[r] += kk; q1[r] += kk * kk; s2[r] += vv; q2[r] += vv * vv;
    }
  }
  float m1[4], r1[4], m2[4], r2[4];
#pragma unroll
  for (int r = 0; r < 4; ++r) {
#pragma unroll
    for (int msk = 1; msk < 16; msk <<= 1) {
      s1[r] += __shfl_xor(s1[r], msk); q1[r] += __shfl_xor(q1[r], msk);
      s2[r] += __shfl_xor(s2[r], msk); q2[r] += __shfl_xor(q2[r], msk);
    }
    m1[r] = s1[r] * (1.f / 512.f);
    r1[r] = rsqrtf(q1[r] * (1.f / 512.f) - m1[r] * m1[r] + 1e-5f);
    m2[r] = s2[r] * (1.f / 512.f);
    r2[r] = rsqrtf(q2[r] * (1.f / 512.f) - m2[r] * m2[r] + 1e-5f);
  }
#pragma unroll
  for (int nf = 0; nf < 32; ++nf) {
    int col = nf * 16 + c;
    float w0 = Pf[512 + col], w1 = Pf[1024 + col], w2 = Pf[1536 + col], bi = Pf[2048 + col];
    float gk = Pf[2560 + col], bk = Pf[3072 + col];
    float gv = Pf[3584 + col], bv = Pf[4096 + col];
#pragma unroll
    for (int r = 0; r < 4; ++r) {
      float kk = acc[nf][r];
      float vv = kk + x0[r] * w0 + x1[r] * w1 + x2[r] * w2 + bi;
      size_t ridx = (size_t)(rowbase + r) * 1024;
      knvn[ridx + col] = f2bf((kk - m1[r]) * r1[r] * gk + bk);
      knvn[ridx + 512 + col] = f2bf((vv - m2[r]) * r2[r] * gv + bv);
    }
  }
}

// ---------------------------------------------------------------------------
// LayerNorm fp32 in [M,512] -> bf16 out, one wave per row
// ---------------------------------------------------------------------------
__global__ __launch_bounds__(256) void ln_kernel(
    const float* __restrict__ in, const float* __restrict__ g,
    const float* __restrict__ b, short* __restrict__ out, int M) {
  int row = blockIdx.x * 4 + (threadIdx.x >> 6);
  if (row >= M) return;
  int lane = threadIdx.x & 63;
  float v[8]; float s = 0, q = 0;
#pragma unroll
  for (int j = 0; j < 8; ++j) {
    v[j] = in[(size_t)row * 512 + lane + 64 * j];
    s += v[j]; q += v[j] * v[j];
  }
  s = wred(s); q = wred(q);
  float m = s * (1.f / 512.f);
  float rs = rsqrtf(q * (1.f / 512.f) - m * m + 1e-5f);
#pragma unroll
  for (int j = 0; j < 8; ++j) {
    int cc = lane + 64 * j;
    out[(size_t)row * 512 + cc] = f2bf((v[j] - m) * rs * g[cc] + b[cc]);
  }
}

// broadcast latents [256,512] -> lat [2048,512] fp32
__global__ void bcast_kernel(const float* __restrict__ latents, float* __restrict__ lat) {
  int i = blockIdx.x * 256 + threadIdx.x;
  lat[i] = latents[i & 131071];
}

// ---------------------------------------------------------------------------
// Shared GEMM epilogue op
// EPI: 0 = bf16 out, 1 = gelu->bf16, 2 = fp32 residual +=, 3 = fp32 out
// ---------------------------------------------------------------------------
template <int EPI>
DEV void epi_store(void* outp, size_t idx, float xv) {
  if (EPI == 0) {
    ((short*)outp)[idx] = f2bf(xv);
  } else if (EPI == 1) {
    float t = 0.7978845608f * (xv + 0.044715f * xv * xv * xv);
    ((short*)outp)[idx] = f2bf(0.5f * xv * (1.f + tanhf(t)));
  } else if (EPI == 2) {
    ((float*)outp)[idx] += xv;
  } else {
    ((float*)outp)[idx] = xv;
  }
}

// ---------------------------------------------------------------------------
// GEMM 128x128 tile, BK=64, 4 waves (2x2). A bf16 [M,*lda]; Wt bf16 [N][K].
// XCD-aware block swizzle (requires gridDim.x*gridDim.y % 8 == 0).
// ---------------------------------------------------------------------------
template <int EPI>
__global__ __launch_bounds__(256) void gemm_kernel(
    const short* __restrict__ A, const short* __restrict__ Wt,
    const float* __restrict__ bias, void* __restrict__ outp,
    int M, int N, int K, int lda, int ldo) {
  __shared__ short Alds[128 * 64];
  __shared__ short Blds[128 * 64];
  int tid = threadIdx.x;
  // XCD swizzle: contiguous chunk of tiles per XCD
  int nwg = gridDim.x * gridDim.y;
  int id = blockIdx.y * gridDim.x + blockIdx.x;
  int cpx = nwg >> 3;
  id = (id & 7) * cpx + (id >> 3);
  int brow = (id / gridDim.x) * 128, bcol = (id % gridDim.x) * 128;
  int lane = tid & 63, wvid = tid >> 6;
  int wr = wvid >> 1, wc = wvid & 1;
  int g = lane >> 4, c = lane & 15;
  floatx4 zf = {0.f, 0.f, 0.f, 0.f};
  floatx4 acc[4][4];
#pragma unroll
  for (int i = 0; i < 4; ++i)
#pragma unroll
    for (int j = 0; j < 4; ++j) acc[i][j] = zf;

  int srow = (lane >> 3), skc = lane & 7;
  for (int k0 = 0; k0 < K; k0 += 64) {
#pragma unroll
    for (int gi = 0; gi < 4; ++gi) {
      int grp = wvid * 4 + gi;
      int row = grp * 8 + srow;
      int sw = ((skc ^ (row & 7)) * 8);
      gload16(&Alds[grp * 512], &A[(size_t)(brow + row) * lda + k0 + sw]);
      gload16(&Blds[grp * 512], &Wt[(size_t)(bcol + row) * K + k0 + sw]);
    }
    __syncthreads();
#pragma unroll
    for (int ks = 0; ks < 2; ++ks) {
      int slot = ((ks * 4 + g) ^ (c & 7)) * 8;
      short8 af[4], bf8[4];
#pragma unroll
      for (int mf = 0; mf < 4; ++mf)
        af[mf] = *(const short8*)&Alds[(wr * 64 + mf * 16 + c) * 64 + slot];
#pragma unroll
      for (int nf = 0; nf < 4; ++nf)
        bf8[nf] = *(const short8*)&Blds[(wc * 64 + nf * 16 + c) * 64 + slot];
#pragma unroll
      for (int mf = 0; mf < 4; ++mf)
#pragma unroll
        for (int nf = 0; nf < 4; ++nf)
          acc[mf][nf] = mfma16(af[mf], bf8[nf], acc[mf][nf]);
    }
    __syncthreads();
  }

#pragma unroll
  for (int mf = 0; mf < 4; ++mf) {
#pragma unroll
    for (int nf = 0; nf < 4; ++nf) {
      int col = bcol + wc * 64 + nf * 16 + c;
      float bv = bias ? bias[col] : 0.f;
      int row0 = brow + wr * 64 + mf * 16 + g * 4;
#pragma unroll
      for (int r = 0; r < 4; ++r)
        epi_store<EPI>(outp, (size_t)(row0 + r) * ldo + col, acc[mf][nf][r] + bv);
    }
  }
}

// ---------------------------------------------------------------------------
// GEMM 64x64 tile. 4 waves (2x2), each wave 32x32.
// ---------------------------------------------------------------------------
template <int EPI>
__global__ __launch_bounds__(256) void gemm64_kernel(
    const short* __restrict__ A, const short* __restrict__ Wt,
    const float* __restrict__ bias, void* __restrict__ outp,
    int M, int N, int K, int lda, int ldo) {
  __shared__ short Alds[64 * 64];
  __shared__ short Blds[64 * 64];
  int tid = threadIdx.x;
  int brow = blockIdx.y * 64, bcol = blockIdx.x * 64;
  int lane = tid & 63, wvid = tid >> 6;
  int wr = wvid >> 1, wc = wvid & 1;
  int g = lane >> 4, c = lane & 15;
  floatx4 zf = {0.f, 0.f, 0.f, 0.f};
  floatx4 acc[2][2];
#pragma unroll
  for (int i = 0; i < 2; ++i)
#pragma unroll
    for (int j = 0; j < 2; ++j) acc[i][j] = zf;

  int srow = (lane >> 3), skc = lane & 7;
  for (int k0 = 0; k0 < K; k0 += 64) {
#pragma unroll
    for (int gi = 0; gi < 2; ++gi) {
      int grp = wvid * 2 + gi;
      int row = grp * 8 + srow;
      int sw = ((skc ^ (row & 7)) * 8);
      gload16(&Alds[grp * 512], &A[(size_t)(brow + row) * lda + k0 + sw]);
      gload16(&Blds[grp * 512], &Wt[(size_t)(bcol + row) * K + k0 + sw]);
    }
    __syncthreads();
#pragma unroll
    for (int ks = 0; ks < 2; ++ks) {
      int slot = ((ks * 4 + g) ^ (c & 7)) * 8;
      short8 af[2], bf8[2];
#pragma unroll
      for (int mf = 0; mf < 2; ++mf)
        af[mf] = *(const short8*)&Alds[(wr * 32 + mf * 16 + c) * 64 + slot];
#pragma unroll
      for (int nf = 0; nf < 2; ++nf)
        bf8[nf] = *(const short8*)&Blds[(wc * 32 + nf * 16 + c) * 64 + slot];
#pragma unroll
      for (int mf = 0; mf < 2; ++mf)
#pragma unroll
        for (int nf = 0; nf < 2; ++nf)
          acc[mf][nf] = mfma16(af[mf], bf8[nf], acc[mf][nf]);
    }
    __syncthreads();
  }

#pragma unroll
  for (int mf = 0; mf < 2; ++mf) {
#pragma unroll
    for (int nf = 0; nf < 2; ++nf) {
      int col = bcol + wc * 32 + nf * 16 + c;
      float bv = bias ? bias[col] : 0.f;
      int row0 = brow + wr * 32 + mf * 16 + g * 4;
#pragma unroll
      for (int r = 0; r < 4; ++r)
        epi_store<EPI>(outp, (size_t)(row0 + r) * ldo + col, acc[mf][nf][r] + bv);
    }
  }
}

// ---------------------------------------------------------------------------
// Split-KV flash attention, 64-row Q tile, 4 waves (wave = 16 q rows).
// Q pre-scaled by DH^-0.5 (folded into Wq). qbrows==0 => q shared across b.
// po[(seg*2048 + b*256 + row)*512 + h*64 + d]; pm/pl[(seg*2048+b*256+row)*8+h]
// ---------------------------------------------------------------------------
__global__ __launch_bounds__(256) void flashsp_kernel(
    const short* __restrict__ q, const short* __restrict__ k,
    const short* __restrict__ v, float* __restrict__ po,
    float* __restrict__ pm, float* __restrict__ pl,
    int qrs, int qbrows, long kvbstride, int kvrstride,
    int seglen, int lognseg) {
  __shared__ short Qs[64 * 64];
  __shared__ short Ks[64 * 64];
  __shared__ short Vt[64 * 72];
  __shared__ short Ps[64 * 72];
  int tid = threadIdx.x;
  int bz = blockIdx.z;
  int b = bz >> lognseg, seg = bz & ((1 << lognseg) - 1);
  int h = blockIdx.y, qt = blockIdx.x;
  int lane = tid & 63, wv = tid >> 6;
  int g = lane >> 4, c = lane & 15;
  int srow = lane >> 3, skc = lane & 7;

#pragma unroll
  for (int gi = 0; gi < 2; ++gi) {
    int grp = wv * 2 + gi;
    int row = grp * 8 + srow;
    int sw = ((skc ^ (row & 7)) * 8);
    gload16(&Qs[grp * 512],
            &q[((size_t)(b * qbrows) + qt * 64 + row) * qrs + h * 64 + sw]);
  }

  float m_[4], l_[4];
  floatx4 zf = {0.f, 0.f, 0.f, 0.f};
  floatx4 o_[4];
#pragma unroll
  for (int r = 0; r < 4; ++r) { m_[r] = -3.0e38f; l_[r] = 0.f; }
#pragma unroll
  for (int f = 0; f < 4; ++f) o_[f] = zf;

  int tbeg = seg * seglen, tend = tbeg + seglen;
  for (int t0 = tbeg; t0 < tend; t0 += 64) {
#pragma unroll
    for (int gi = 0; gi < 2; ++gi) {
      int grp = wv * 2 + gi;
      int row = grp * 8 + srow;
      int sw = ((skc ^ (row & 7)) * 8);
      gload16(&Ks[grp * 512],
              &k[(size_t)b * kvbstride + (size_t)(t0 + row) * kvrstride + h * 64 + sw]);
    }
#pragma unroll
    for (int it = 0; it < 2; ++it) {
      int ch = tid + it * 256;
      int j = ch >> 3, f0 = (ch & 7) * 8, mm = ch & 7, tg = j >> 3;
      short8 tv = *(const short8*)&v[(size_t)b * kvbstride + (size_t)(t0 + j) * kvrstride + h * 64 + f0];
#pragma unroll
      for (int jj = 0; jj < 8; ++jj)
        Vt[(f0 + jj) * 72 + ((tg ^ mm) * 8) + (j & 7)] = tv[jj];
    }
    __syncthreads();

    floatx4 s[4];
#pragma unroll
    for (int f = 0; f < 4; ++f) s[f] = zf;
#pragma unroll
    for (int ks = 0; ks < 2; ++ks) {
      int slot = ((ks * 4 + g) ^ (c & 7)) * 8;
      short8 a = *(const short8*)&Qs[(wv * 16 + c) * 64 + slot];
#pragma unroll
      for (int f = 0; f < 4; ++f) {
        short8 b8 = *(const short8*)&Ks[(f * 16 + c) * 64 + slot];
        s[f] = mfma16(a, b8, s[f]);
      }
    }

    float nm[4], sf[4], rs[4];
#pragma unroll
    for (int r = 0; r < 4; ++r) {
      float t = fmaxf(fmaxf(s[0][r], s[1][r]), fmaxf(s[2][r], s[3][r]));
#pragma unroll
      for (int msk = 1; msk < 16; msk <<= 1) t = fmaxf(t, __shfl_xor(t, msk));
      nm[r] = fmaxf(m_[r], t);
      sf[r] = __expf(m_[r] - nm[r]);
      rs[r] = 0.f;
    }
#pragma unroll
    for (int f = 0; f < 4; ++f)
#pragma unroll
      for (int r = 0; r < 4; ++r) {
        float p = __expf(s[f][r] - nm[r]);
        s[f][r] = p; rs[r] += p;
      }
#pragma unroll
    for (int r = 0; r < 4; ++r) {
#pragma unroll
      for (int msk = 1; msk < 16; msk <<= 1) rs[r] += __shfl_xor(rs[r], msk);
      l_[r] = l_[r] * sf[r] + rs[r];
      m_[r] = nm[r];
    }
#pragma unroll
    for (int f = 0; f < 4; ++f)
#pragma unroll
      for (int r = 0; r < 4; ++r) o_[f][r] *= sf[r];
#pragma unroll
    for (int f = 0; f < 4; ++f)
#pragma unroll
      for (int r = 0; r < 4; ++r)
        Ps[(wv * 16 + g * 4 + r) * 72 + f * 16 + c] = f2bf(s[f][r]);
    __syncthreads();
#pragma unroll
    for (int ks = 0; ks < 2; ++ks) {
      short8 pa = *(const short8*)&Ps[(wv * 16 + c) * 72 + ks * 32 + g * 8];
#pragma unroll
      for (int f = 0; f < 4; ++f) {
        int mm = (2 * f + (c >> 3)) & 7;
        short8 vb = *(const short8*)&Vt[(f * 16 + c) * 72 + ((ks * 4 + g) ^ mm) * 8];
        o_[f] = mfma16(pa, vb, o_[f]);
      }
    }
    __syncthreads();
  }

#pragma unroll
  for (int f = 0; f < 4; ++f)
#pragma unroll
    for (int r = 0; r < 4; ++r) {
      int row = qt * 64 + wv * 16 + g * 4 + r;
      size_t grow = (size_t)seg * 2048 + b * 256 + row;
      po[grow * 512 + h * 64 + f * 16 + c] = o_[f][r];
      if (f == 0 && c == 0) {
        pm[grow * 8 + h] = m_[r];
        pl[grow * 8 + h] = l_[r];
      }
    }
}

// ---------------------------------------------------------------------------
// Combine NSEG partial attention results -> bf16 out [2048,512]
// ---------------------------------------------------------------------------
template <int NSEG>
__global__ __launch_bounds__(256) void fcomb_kernel(
    const float* __restrict__ po, const float* __restrict__ pm,
    const float* __restrict__ pl, short* __restrict__ out) {
  int idx = blockIdx.x * 256 + threadIdx.x;  // over 2048*512
  int grow = idx >> 9, col = idx & 511, h = col >> 6;
  float ms[NSEG];
  float M = -3.0e38f;
#pragma unroll
  for (int s = 0; s < NSEG; ++s) {
    ms[s] = pm[((size_t)s * 2048 + grow) * 8 + h];
    M = fmaxf(M, ms[s]);
  }
  float L = 0.f, acc = 0.f;
#pragma unroll
  for (int s = 0; s < NSEG; ++s) {
    float w = __expf(ms[s] - M);
    L += w * pl[((size_t)s * 2048 + grow) * 8 + h];
    acc += w * po[((size_t)s * 2048 + grow) * 512 + col];
  }
  out[idx] = f2bf(acc / L);
}

// ---------------------------------------------------------------------------
extern "C" void kernel_launch(void* const* d_in, const int* in_sizes, int n_in,
                              void* d_out, int out_size, void* d_ws, size_t ws_size,
                              hipStream_t stream) {
  const float* x       = (const float*)d_in[0];
  const float* pos     = (const float*)d_in[1];
  const float* W_pos   = (const float*)d_in[2];
  const float* b_pos   = (const float*)d_in[3];
  const float* W_in    = (const float*)d_in[4];
  const float* b_in    = (const float*)d_in[5];
  const float* latents = (const float*)d_in[6];
  const float* lnq_g   = (const float*)d_in[7];
  const float* lnq_b   = (const float*)d_in[8];
  const float* lnk_g   = (const float*)d_in[9];
  const float* lnk_b   = (const float*)d_in[10];
  const float* lnv_g   = (const float*)d_in[11];
  const float* lnv_b   = (const float*)d_in[12];
  const float* cWq     = (const float*)d_in[13];
  const float* cWk     = (const float*)d_in[14];
  const float* cWv     = (const float*)d_in[15];
  const float* cWo     = (const float*)d_in[16];
  const float* c_bo    = (const float*)d_in[17];
  const float* ln1_g   = (const float*)d_in[18];
  const float* ln1_b   = (const float*)d_in[19];
  const float* sWq     = (const float*)d_in[20];
  const float* sWkv    = (const float*)d_in[21];
  const float* sWo     = (const float*)d_in[22];
  const float* s_bo    = (const float*)d_in[23];
  const float* ln2_g   = (const float*)d_in[24];
  const float* ln2_b   = (const float*)d_in[25];
  const float* fW1     = (const float*)d_in[26];
  const float* f_b1    = (const float*)d_in[27];
  const float* fW2     = (const float*)d_in[28];
  const float* f_b2    = (const float*)d_in[29];
  const float* lnf_g   = (const float*)d_in[30];
  const float* lnf_b   = (const float*)d_in[31];
  const float* Wb      = (const float*)d_in[32];
  const float* bbv     = (const float*)d_in[33];
  float* outp = (float*)d_out;

  // bf16 transposed weight offsets (elements)
  size_t W = 0;
  size_t o_cWq = W; W += 512 * 512;
  size_t o_cWk = W; W += 512 * 512;
  size_t o_cWv = W; W += 512 * 512;
  size_t o_cWo = W; W += 512 * 512;
  size_t o_Wb  = W; W += 64 * 512;
  size_t o_Wpos = W; W += 512 * 64;
  size_t o_sQKV[6], o_sWo[6], o_fW1[6], o_fW2[6];
  for (int i = 0; i < 6; ++i) {
    o_sQKV[i] = W; W += 1536 * 512;   // q rows 0..511 (pre-scaled), kv rows 512..1535
    o_sWo[i]  = W; W += 512 * 512;
    o_fW1[i]  = W; W += 2048 * 512;
    o_fW2[i]  = W; W += 512 * 2048;
  }
  MatTable T;
  int nm = 0;
  auto add = [&](const float* s, int K, int N, int kp, size_t off, float sc) {
    T.m[nm].src = s; T.m[nm].K = K; T.m[nm].N = N; T.m[nm].kp = kp;
    T.m[nm].off = (int)off; T.m[nm].scale = sc; ++nm;
  };
  const float SC = 0.125f;  // DH^-0.5 folded into Wq
  add(cWq, 512, 512, 512, o_cWq, SC); add(cWk, 512, 512, 512, o_cWk, 1.f);
  add(cWv, 512, 512, 512, o_cWv, 1.f); add(cWo, 512, 512, 512, o_cWo, 1.f);
  add(Wb, 512, 64, 512, o_Wb, 1.f);
  add(W_pos, 48, 512, 64, o_Wpos, 1.f);
  for (int i = 0; i < 6; ++i) {
    add(sWq  + (size_t)i * 512 * 512,  512, 512,  512, o_sQKV[i], SC);
    add(sWkv + (size_t)i * 512 * 1024, 512, 1024, 512, o_sQKV[i] + 512 * 512, 1.f);
    add(sWo  + (size_t)i * 512 * 512,  512, 512,  512, o_sWo[i], 1.f);
    add(fW1  + (size_t)i * 512 * 2048, 512, 2048, 512, o_fW1[i], 1.f);
    add(fW2  + (size_t)i * 2048 * 512, 2048, 512, 2048, o_fW2[i], 1.f);
  }

  // workspace carve
  char* p = (char*)d_ws;
  auto carve = [&](size_t bytes) {
    char* r = p; p += (bytes + 255) & ~(size_t)255; return r;
  };
  short* wtb   = (short*)carve(W * 2);                     // ~40MB
  short* enc   = (short*)carve((size_t)32768 * 64 * 2);    // 4MB
  short* knvn  = (short*)carve((size_t)32768 * 1024 * 2);  // 64MB  [k | v]
  short* kvc   = (short*)carve((size_t)32768 * 1024 * 2);  // 64MB  [K | V]
  short* latn0 = (short*)carve(262144);
  short* qc    = (short*)carve(262144);
  float* lat   = (float*)carve(4194304);
  float* pm    = (float*)carve(1048576);
  float* pl    = (float*)carve(1048576);
  // aliases into dead regions:
  short* attno = enc;                                  // enc dead after embed2
  float* po    = (float*)knvn;                         // knvn dead after projections
  short* h     = (short*)((char*)knvn + 36 * 1048576);
  short* qkv   = (short*)((char*)knvn + 40 * 1048576);
  short* ffh   = (short*)((char*)knvn + 48 * 1048576);

  wtrans_kernel<<<dim3(1024, 36), 256, 0, stream>>>(T, wtb);
  enc_kernel<<<1024, 256, 0, stream>>>(pos, enc);
  embed2_kernel<<<256, 512, 0, stream>>>(enc, wtb + o_Wpos, b_pos, W_in, b_in, x,
                                         lnk_g, lnk_b, lnv_g, lnv_b, knvn);
  bcast_kernel<<<4096, 256, 0, stream>>>(latents, lat);
  ln_kernel<<<64, 256, 0, stream>>>(latents, lnq_g, lnq_b, latn0, 256);
  gemm64_kernel<0><<<dim3(8, 4), 256, 0, stream>>>(latn0, wtb + o_cWq, nullptr, qc, 256, 512, 512, 512, 512);
  gemm_kernel<0><<<dim3(4, 256), 256, 0, stream>>>(knvn, wtb + o_cWk, nullptr, kvc, 32768, 512, 512, 1024, 1024);
  gemm_kernel<0><<<dim3(4, 256), 256, 0, stream>>>(knvn + 512, wtb + o_cWv, nullptr, kvc + 512, 32768, 512, 512, 1024, 1024);
  // cross attention: 8 KV segments of 512 tokens; qc shared across b (qbrows=0)
  flashsp_kernel<<<dim3(4, 8, 64), 256, 0, stream>>>(qc, kvc, kvc + 512, po, pm, pl,
                                                     512, 0, (long)4096 * 1024, 1024, 512, 3);
  fcomb_kernel<8><<<4096, 256, 0, stream>>>(po, pm, pl, attno);
  gemm64_kernel<2><<<dim3(8, 32), 256, 0, stream>>>(attno, wtb + o_cWo, c_bo, lat, 2048, 512, 512, 512, 512);

  for (int i = 0; i < 6; ++i) {
    ln_kernel<<<512, 256, 0, stream>>>(lat, ln1_g + i * 512, ln1_b + i * 512, h, 2048);
    gemm64_kernel<0><<<dim3(24, 32), 256, 0, stream>>>(h, wtb + o_sQKV[i], nullptr, qkv, 2048, 1536, 512, 512, 1536);
    // self attention: 2 KV segments of 128 tokens (per-batch q)
    flashsp_kernel<<<dim3(4, 8, 16), 256, 0, stream>>>(qkv, qkv + 512, qkv + 1024, po, pm, pl,
                                                       1536, 256, (long)256 * 1536, 1536, 128, 1);
    fcomb_kernel<2><<<4096, 256, 0, stream>>>(po, pm, pl, attno);
    gemm64_kernel<2><<<dim3(8, 32), 256, 0, stream>>>(attno, wtb + o_sWo[i], s_bo + i * 512, lat, 2048, 512, 512, 512, 512);
    ln_kernel<<<512, 256, 0, stream>>>(lat, ln2_g + i * 512, ln2_b + i * 512, h, 2048);
    gemm_kernel<1><<<dim3(16, 16), 256, 0, stream>>>(h, wtb + o_fW1[i], f_b1 + i * 2048, ffh, 2048, 2048, 512, 512, 2048);
    gemm64_kernel<2><<<dim3(8, 32), 256, 0, stream>>>(ffh, wtb + o_fW2[i], f_b2 + i * 512, lat, 2048, 512, 2048, 2048, 512);
  }
  ln_kernel<<<512, 256, 0, stream>>>(lat, lnf_g, lnf_b, h, 2048);
  gemm64_kernel<3><<<dim3(1, 32), 256, 0, stream>>>(h, wtb + o_Wb, bbv, outp, 2048, 64, 512, 512, 64);
}